// Round 11
// baseline (76.909 us; speedup 1.0000x reference)
//
#include <hip/hip_runtime.h>

#define BH  64
#define SEQ 4096
#define DH  64
#define NCHUNK 16
#define CROWS  (SEQ / NCHUNK)   // 256 rows per chunk
#define NT     (CROWS / 32)     // 8 tiles of 32 rows

typedef __attribute__((ext_vector_type(8))) short bf16x8v;  // 8 bf16 (4 VGPR)
typedef __attribute__((ext_vector_type(4))) float f32x4v;   // MFMA acc

// fp32 -> bf16, round-to-nearest-even
__device__ __forceinline__ short f2bf(float x) {
  unsigned u = __float_as_uint(x);
  return (short)((u + 0x7FFFu + ((u >> 16) & 1u)) >> 16);
}

// async global->LDS, 16B per lane; LDS dest = wave-uniform base + lane*16
__device__ __forceinline__ void gload_lds16(const float* g, float* l) {
  __builtin_amdgcn_global_load_lds(
      (const __attribute__((address_space(1))) void*)g,
      (__attribute__((address_space(3))) void*)l, 16, 0, 0);
}

// ---------------------------------------------------------------------------
// Kernel 1: partial kv = k^T v over a 256-row chunk. One (b,h,chunk)/block.
// 256 threads = 4 waves; wave w owns quadrant (d0=(w&1)*32, e0=(w>>1)*32)
// as 2x2 MFMA 16x16 tiles -> no cross-wave reduction.
// Staging: global_load_lds dwordx4 into double-buffered LDS (32 KB total,
// linear layout). Fragment reads from LDS (ds_read_b32, 4-way conflict ok),
// fp32->bf16 cvt in-reg, 4 MFMA per 32-row tile per wave.
// Compute (~450 cyc/wave/tile) << staging (~1600 cyc HBM) -> HBM-bound.
// Fragment mapping & C-write verified on HW in round 10.
// ---------------------------------------------------------------------------
__global__ __launch_bounds__(256, 4) void kv_partial_kernel(
    const float* __restrict__ k, const float* __restrict__ v,
    float* __restrict__ partial) {
  const int t = threadIdx.x;
  const int bh = blockIdx.x >> 4;             // / NCHUNK
  const int chunk = blockIdx.x & (NCHUNK - 1);

  const int l  = t & 63;
  const int w  = t >> 6;
  const int lg = l >> 4;     // s-subgroup 0..3
  const int ln = l & 15;     // column within 16-wide tile
  const int d0 = (w & 1) * 32;
  const int e0 = (w >> 1) * 32;

  const float* kb = k + (size_t)bh * SEQ * DH + (size_t)chunk * CROWS * DH;
  const float* vb = v + (size_t)bh * SEQ * DH + (size_t)chunk * CROWS * DH;

  // floats: k buf0 [0,2048) | k buf1 [2048,4096) | v buf0 [4096,6144) | v buf1 [6144,8192)
  __shared__ float smem[8192];

  // stage tile tt (32 rows x 64 cols x fp32 = 2048 floats/tensor) into buf tt&1
  auto STAGE = [&](int tt) {
    const int buf = tt & 1;
    const size_t goff = (size_t)tt * 32 * DH;
    // 2 insts per tensor: inst i covers floats [i*1024, i*1024+1024)
    const int wo = w * 256;   // wave's 256-float span within each 1024 half
#pragma unroll
    for (int i = 0; i < 2; ++i) {
      gload_lds16(kb + goff + i * 1024 + wo + l * 4,
                  smem + buf * 2048 + i * 1024 + wo);
      gload_lds16(vb + goff + i * 1024 + wo + l * 4,
                  smem + 4096 + buf * 2048 + i * 1024 + wo);
    }
  };

  f32x4v acc00 = {0.f, 0.f, 0.f, 0.f};
  f32x4v acc01 = acc00, acc10 = acc00, acc11 = acc00;

  STAGE(0);
  asm volatile("s_waitcnt vmcnt(0)" ::: "memory");
  __syncthreads();

  for (int tt = 0; tt < NT; ++tt) {
    if (tt + 1 < NT) STAGE(tt + 1);

    const float* ksb = smem + (tt & 1) * 2048;
    const float* vsb = smem + 4096 + (tt & 1) * 2048;

    bf16x8v a0, a1, b0, b1;
#pragma unroll
    for (int j = 0; j < 8; ++j) {
      const int r = (lg * 8 + j) * 64;
      a0[j] = f2bf(ksb[r + d0 + ln]);
      a1[j] = f2bf(ksb[r + d0 + 16 + ln]);
      b0[j] = f2bf(vsb[r + e0 + ln]);
      b1[j] = f2bf(vsb[r + e0 + 16 + ln]);
    }

    acc00 = __builtin_amdgcn_mfma_f32_16x16x32_bf16(a0, b0, acc00, 0, 0, 0);
    acc01 = __builtin_amdgcn_mfma_f32_16x16x32_bf16(a0, b1, acc01, 0, 0, 0);
    acc10 = __builtin_amdgcn_mfma_f32_16x16x32_bf16(a1, b0, acc10, 0, 0, 0);
    acc11 = __builtin_amdgcn_mfma_f32_16x16x32_bf16(a1, b1, acc11, 0, 0, 0);

    asm volatile("s_waitcnt vmcnt(0)" ::: "memory");
    __syncthreads();
  }

  // C/D layout (HW-verified round 10): col = lane&15, row = (lane>>4)*4 + reg
  float* pb = partial + (size_t)blockIdx.x * (DH * DH);
  const int rbase = lg * 4;
#pragma unroll
  for (int r = 0; r < 4; ++r) {
    pb[(d0 +  0 + rbase + r) * 64 + e0 +  0 + ln] = acc00[r];
    pb[(d0 +  0 + rbase + r) * 64 + e0 + 16 + ln] = acc01[r];
    pb[(d0 + 16 + rbase + r) * 64 + e0 +  0 + ln] = acc10[r];
    pb[(d0 + 16 + rbase + r) * 64 + e0 + 16 + ln] = acc11[r];
  }
}

// ---------------------------------------------------------------------------
// Kernel 2: reduce partials -> kvf [BH][64*64]. 256 blocks x 256 threads
// covers 65536 float4 slots.
// ---------------------------------------------------------------------------
__global__ __launch_bounds__(256) void kv_reduce_kernel(
    const float* __restrict__ partial, float* __restrict__ kvf) {
  const int gid = blockIdx.x * 256 + threadIdx.x;
  const int bh = gid >> 10;
  const int idx = gid & 1023;
  float4 s = {0.f, 0.f, 0.f, 0.f};
  for (int c = 0; c < NCHUNK; ++c) {
    const float4* p = (const float4*)(partial + ((size_t)bh * NCHUNK + c) * (DH * DH));
    float4 x = p[idx];
    s.x += x.x; s.y += x.y; s.z += x.z; s.w += x.w;
  }
  ((float4*)kvf)[gid] = s;
}

// ---------------------------------------------------------------------------
// Kernel 3: out = q @ kv. Block = 64 q-rows. Thread = 1 row x 16 cols.
// Entire q row hoisted to registers up front; kv in LDS, broadcast reads.
// At BW roofline (~17 us) -- unchanged.
// ---------------------------------------------------------------------------
__global__ __launch_bounds__(256) void out_kernel(
    const float* __restrict__ q, const float* __restrict__ kvf,
    float* __restrict__ out) {
  const int t = threadIdx.x;
  const int bh = blockIdx.x >> 6;
  const int rb = blockIdx.x & 63;
  const int row = rb * 64 + (t >> 2);
  const int c0 = (t & 3) * 16;

  __shared__ float kv_lds[64 * 64];

  const float4* gkv4 = (const float4*)(kvf + (size_t)bh * (DH * DH));
  float4* kv4 = (float4*)kv_lds;
#pragma unroll
  for (int j = 0; j < 4; ++j) kv4[t + j * 256] = gkv4[t + j * 256];

  const float* qrow = q + (size_t)bh * SEQ * DH + (size_t)row * DH;
  float4 qv[16];
#pragma unroll
  for (int i = 0; i < 16; ++i) qv[i] = *(const float4*)&qrow[i * 4];

  __syncthreads();

  float acc[16];
#pragma unroll
  for (int j = 0; j < 16; ++j) acc[j] = 0.f;

#pragma unroll
  for (int dc = 0; dc < 16; ++dc) {
    float qs[4] = {qv[dc].x, qv[dc].y, qv[dc].z, qv[dc].w};
#pragma unroll
    for (int dd = 0; dd < 4; ++dd) {
      const float* kr = &kv_lds[(dc * 4 + dd) * 64 + c0];
      float4 k0 = *(const float4*)&kr[0];
      float4 k1 = *(const float4*)&kr[4];
      float4 k2 = *(const float4*)&kr[8];
      float4 k3 = *(const float4*)&kr[12];
      const float qsv = qs[dd];
      acc[0]  += qsv * k0.x; acc[1]  += qsv * k0.y;
      acc[2]  += qsv * k0.z; acc[3]  += qsv * k0.w;
      acc[4]  += qsv * k1.x; acc[5]  += qsv * k1.y;
      acc[6]  += qsv * k1.z; acc[7]  += qsv * k1.w;
      acc[8]  += qsv * k2.x; acc[9]  += qsv * k2.y;
      acc[10] += qsv * k2.z; acc[11] += qsv * k2.w;
      acc[12] += qsv * k3.x; acc[13] += qsv * k3.y;
      acc[14] += qsv * k3.z; acc[15] += qsv * k3.w;
    }
  }

  float* ob = out + (size_t)bh * SEQ * DH + (size_t)row * DH + c0;
#pragma unroll
  for (int j = 0; j < 4; ++j) {
    float4 w = {acc[4 * j + 0], acc[4 * j + 1], acc[4 * j + 2], acc[4 * j + 3]};
    *(float4*)&ob[4 * j] = w;
  }
}

// ---------------------------------------------------------------------------
extern "C" void kernel_launch(void* const* d_in, const int* in_sizes, int n_in,
                              void* d_out, int out_size, void* d_ws, size_t ws_size,
                              hipStream_t stream) {
  const float* q = (const float*)d_in[0];
  const float* k = (const float*)d_in[1];
  const float* v = (const float*)d_in[2];
  float* out = (float*)d_out;

  float* kvf = (float*)d_ws;                      // [BH][64*64] = 1 MB
  float* partial = kvf + (size_t)BH * DH * DH;    // [BH*NCHUNK][64*64] = 16 MB

  hipLaunchKernelGGL(kv_partial_kernel, dim3(BH * NCHUNK), dim3(256), 0, stream,
                     k, v, partial);
  hipLaunchKernelGGL(kv_reduce_kernel, dim3(256), dim3(256), 0, stream,
                     partial, kvf);
  hipLaunchKernelGGL(out_kernel, dim3(BH * 64), dim3(256), 0, stream,
                     q, kvf, out);
}

// Round 12
// 76.479 us; speedup vs baseline: 1.0056x; 1.0056x over previous
//
#include <hip/hip_runtime.h>

#define BH  64
#define SEQ 4096
#define DH  64
#define NCHUNK 16
#define CROWS  (SEQ / NCHUNK)   // 256 rows per chunk
#define NT     (CROWS / 32)     // 8 tiles of 32 rows

typedef __attribute__((ext_vector_type(8))) short bf16x8v;  // 8 bf16 (4 VGPR)
typedef __attribute__((ext_vector_type(4))) float f32x4v;   // MFMA acc

// fp32 -> bf16, round-to-nearest-even
__device__ __forceinline__ short f2bf(float x) {
  unsigned u = __float_as_uint(x);
  return (short)((u + 0x7FFFu + ((u >> 16) & 1u)) >> 16);
}

// async global->LDS, 16B per lane; LDS dest = wave-uniform base + lane*16
__device__ __forceinline__ void gload_lds16(const float* g, float* l) {
  __builtin_amdgcn_global_load_lds(
      (const __attribute__((address_space(1))) void*)g,
      (__attribute__((address_space(3))) void*)l, 16, 0, 0);
}

// ---------------------------------------------------------------------------
// Kernel 1: partial kv = k^T v over a 256-row chunk. One (b,h,chunk)/block.
// 256 threads = 4 waves; wave w owns quadrant (d0=(w&1)*32, e0=(w>>1)*32)
// as 2x2 MFMA 16x16 tiles -> no cross-wave reduction.
// Staging: global_load_lds dwordx4 into a 3-buffer LDS ring (48 KB), COUNTED
// vmcnt(4) -> tile tt+1's loads stay in flight across the barrier (never
// drain to 0 in-loop). 2 tiles (32 KB) always outstanding per block.
// Compute per tile (~500 cyc/wave) << staging BW time (~1600 cyc) -> the
// kernel runs at memory rate. Fragment mapping HW-verified (round 10/11).
// Per-wave-symmetric staging makes counted vmcnt race-free (round 8).
// ---------------------------------------------------------------------------
__global__ __launch_bounds__(256) void kv_partial_kernel(
    const float* __restrict__ k, const float* __restrict__ v,
    float* __restrict__ partial) {
  const int t = threadIdx.x;
  const int bh = blockIdx.x >> 4;             // / NCHUNK
  const int chunk = blockIdx.x & (NCHUNK - 1);

  const int l  = t & 63;
  const int w  = t >> 6;
  const int lg = l >> 4;     // s-subgroup 0..3
  const int ln = l & 15;     // column within 16-wide tile
  const int d0 = (w & 1) * 32;
  const int e0 = (w >> 1) * 32;

  const float* kb = k + (size_t)bh * SEQ * DH + (size_t)chunk * CROWS * DH;
  const float* vb = v + (size_t)bh * SEQ * DH + (size_t)chunk * CROWS * DH;

  // floats: k bufs [0, 6144) | v bufs [6144, 12288)   (3 x 8 KB each tensor)
  __shared__ float smem[12288];

  // stage tile tt (32 rows x 64 f32 = 2048 floats per tensor) into ring buf
  auto STAGE = [&](int tt, int buf) {
    const size_t goff = (size_t)tt * 32 * DH;
    const int wo = w * 256;   // wave's 256-float span within each 1024 half
#pragma unroll
    for (int i = 0; i < 2; ++i) {
      gload_lds16(kb + goff + i * 1024 + wo + l * 4,
                  smem + buf * 2048 + i * 1024 + wo);
      gload_lds16(vb + goff + i * 1024 + wo + l * 4,
                  smem + 6144 + buf * 2048 + i * 1024 + wo);
    }
  };

  f32x4v acc00 = {0.f, 0.f, 0.f, 0.f};
  f32x4v acc01 = acc00, acc10 = acc00, acc11 = acc00;

  // prologue: 2 tiles in flight (8 VMEM insts per wave)
  STAGE(0, 0);
  STAGE(1, 1);

#pragma unroll
  for (int tt = 0; tt < NT; ++tt) {
    // tile tt resident when this wave's oldest 4 insts are done + barrier
    if (tt + 1 < NT) {
      asm volatile("s_waitcnt vmcnt(4)" ::: "memory");
    } else {
      asm volatile("s_waitcnt vmcnt(0)" ::: "memory");
    }
    __builtin_amdgcn_s_barrier();
    __builtin_amdgcn_sched_barrier(0);

    if (tt + 2 < NT) STAGE(tt + 2, (tt + 2) % 3);

    const float* ksb = smem + (tt % 3) * 2048;
    const float* vsb = smem + 6144 + (tt % 3) * 2048;

    bf16x8v a0, a1, b0, b1;
#pragma unroll
    for (int j = 0; j < 8; ++j) {
      const int r = (lg * 8 + j) * 64;
      a0[j] = f2bf(ksb[r + d0 + ln]);
      a1[j] = f2bf(ksb[r + d0 + 16 + ln]);
      b0[j] = f2bf(vsb[r + e0 + ln]);
      b1[j] = f2bf(vsb[r + e0 + 16 + ln]);
    }

    acc00 = __builtin_amdgcn_mfma_f32_16x16x32_bf16(a0, b0, acc00, 0, 0, 0);
    acc01 = __builtin_amdgcn_mfma_f32_16x16x32_bf16(a0, b1, acc01, 0, 0, 0);
    acc10 = __builtin_amdgcn_mfma_f32_16x16x32_bf16(a1, b0, acc10, 0, 0, 0);
    acc11 = __builtin_amdgcn_mfma_f32_16x16x32_bf16(a1, b1, acc11, 0, 0, 0);
  }

  // C/D layout (HW-verified): col = lane&15, row = (lane>>4)*4 + reg
  float* pb = partial + (size_t)blockIdx.x * (DH * DH);
  const int rbase = lg * 4;
#pragma unroll
  for (int r = 0; r < 4; ++r) {
    pb[(d0 +  0 + rbase + r) * 64 + e0 +  0 + ln] = acc00[r];
    pb[(d0 +  0 + rbase + r) * 64 + e0 + 16 + ln] = acc01[r];
    pb[(d0 + 16 + rbase + r) * 64 + e0 +  0 + ln] = acc10[r];
    pb[(d0 + 16 + rbase + r) * 64 + e0 + 16 + ln] = acc11[r];
  }
}

// ---------------------------------------------------------------------------
// Kernel 2: reduce partials -> kvf [BH][64*64]. 256 blocks x 256 threads
// covers 65536 float4 slots.
// ---------------------------------------------------------------------------
__global__ __launch_bounds__(256) void kv_reduce_kernel(
    const float* __restrict__ partial, float* __restrict__ kvf) {
  const int gid = blockIdx.x * 256 + threadIdx.x;
  const int bh = gid >> 10;
  const int idx = gid & 1023;
  float4 s = {0.f, 0.f, 0.f, 0.f};
  for (int c = 0; c < NCHUNK; ++c) {
    const float4* p = (const float4*)(partial + ((size_t)bh * NCHUNK + c) * (DH * DH));
    float4 x = p[idx];
    s.x += x.x; s.y += x.y; s.z += x.z; s.w += x.w;
  }
  ((float4*)kvf)[gid] = s;
}

// ---------------------------------------------------------------------------
// Kernel 3: out = q @ kv. Block = 64 q-rows. Thread = 1 row x 16 cols.
// Entire q row hoisted to registers up front; kv in LDS, broadcast reads.
// At its BW roofline (~18 us) -- unchanged.
// ---------------------------------------------------------------------------
__global__ __launch_bounds__(256) void out_kernel(
    const float* __restrict__ q, const float* __restrict__ kvf,
    float* __restrict__ out) {
  const int t = threadIdx.x;
  const int bh = blockIdx.x >> 6;
  const int rb = blockIdx.x & 63;
  const int row = rb * 64 + (t >> 2);
  const int c0 = (t & 3) * 16;

  __shared__ float kv_lds[64 * 64];

  const float4* gkv4 = (const float4*)(kvf + (size_t)bh * (DH * DH));
  float4* kv4 = (float4*)kv_lds;
#pragma unroll
  for (int j = 0; j < 4; ++j) kv4[t + j * 256] = gkv4[t + j * 256];

  const float* qrow = q + (size_t)bh * SEQ * DH + (size_t)row * DH;
  float4 qv[16];
#pragma unroll
  for (int i = 0; i < 16; ++i) qv[i] = *(const float4*)&qrow[i * 4];

  __syncthreads();

  float acc[16];
#pragma unroll
  for (int j = 0; j < 16; ++j) acc[j] = 0.f;

#pragma unroll
  for (int dc = 0; dc < 16; ++dc) {
    float qs[4] = {qv[dc].x, qv[dc].y, qv[dc].z, qv[dc].w};
#pragma unroll
    for (int dd = 0; dd < 4; ++dd) {
      const float* kr = &kv_lds[(dc * 4 + dd) * 64 + c0];
      float4 k0 = *(const float4*)&kr[0];
      float4 k1 = *(const float4*)&kr[4];
      float4 k2 = *(const float4*)&kr[8];
      float4 k3 = *(const float4*)&kr[12];
      const float qsv = qs[dd];
      acc[0]  += qsv * k0.x; acc[1]  += qsv * k0.y;
      acc[2]  += qsv * k0.z; acc[3]  += qsv * k0.w;
      acc[4]  += qsv * k1.x; acc[5]  += qsv * k1.y;
      acc[6]  += qsv * k1.z; acc[7]  += qsv * k1.w;
      acc[8]  += qsv * k2.x; acc[9]  += qsv * k2.y;
      acc[10] += qsv * k2.z; acc[11] += qsv * k2.w;
      acc[12] += qsv * k3.x; acc[13] += qsv * k3.y;
      acc[14] += qsv * k3.z; acc[15] += qsv * k3.w;
    }
  }

  float* ob = out + (size_t)bh * SEQ * DH + (size_t)row * DH + c0;
#pragma unroll
  for (int j = 0; j < 4; ++j) {
    float4 w = {acc[4 * j + 0], acc[4 * j + 1], acc[4 * j + 2], acc[4 * j + 3]};
    *(float4*)&ob[4 * j] = w;
  }
}

// ---------------------------------------------------------------------------
extern "C" void kernel_launch(void* const* d_in, const int* in_sizes, int n_in,
                              void* d_out, int out_size, void* d_ws, size_t ws_size,
                              hipStream_t stream) {
  const float* q = (const float*)d_in[0];
  const float* k = (const float*)d_in[1];
  const float* v = (const float*)d_in[2];
  float* out = (float*)d_out;

  float* kvf = (float*)d_ws;                      // [BH][64*64] = 1 MB
  float* partial = kvf + (size_t)BH * DH * DH;    // [BH*NCHUNK][64*64] = 16 MB

  hipLaunchKernelGGL(kv_partial_kernel, dim3(BH * NCHUNK), dim3(256), 0, stream,
                     k, v, partial);
  hipLaunchKernelGGL(kv_reduce_kernel, dim3(256), dim3(256), 0, stream,
                     partial, kvf);
  hipLaunchKernelGGL(out_kernel, dim3(BH * 64), dim3(256), 0, stream,
                     q, kvf, out);
}